// Round 8
// baseline (211.730 us; speedup 1.0000x reference)
//
#include <hip/hip_runtime.h>
#include <math.h>

typedef __attribute__((ext_vector_type(8))) short bf16x8;
typedef __attribute__((ext_vector_type(4))) float f32x4;
typedef unsigned short u16;
typedef unsigned int u32;

static __device__ __forceinline__ u16 f2bf(float f) {
    unsigned u = __float_as_uint(f);
    unsigned r = (u + 0x7fff + ((u >> 16) & 1)) >> 16;  // RNE
    return (u16)r;
}
static __device__ __forceinline__ float bf2f(u16 h) {
    return __uint_as_float(((unsigned)h) << 16);
}
static __device__ __forceinline__ float pk_lo(u32 u) { return __uint_as_float(u << 16); }
static __device__ __forceinline__ float pk_hi(u32 u) { return __uint_as_float(u & 0xffff0000u); }

// ---------------- init: zero counts + pack weights (one dispatch) ----------------
__global__ void init_k(int* __restrict__ counts, int n, int gN,
                       const float* __restrict__ W0, const float* __restrict__ W1,
                       const float* __restrict__ W2,
                       u16* __restrict__ w0hi, u16* __restrict__ w0lo,
                       u16* __restrict__ w1hi, u16* __restrict__ w1lo,
                       u16* __restrict__ w2hi, u16* __restrict__ w2lo) {
    int b = blockIdx.x;
    if (b < gN) {
        int i = b * 256 + threadIdx.x;
        if (i < n) counts[i] = 0;
        return;
    }
    int i = (b - gN) * 256 + threadIdx.x;
    const float* W; u16 *hi, *lo; int COLS, cin, idx;
    if (i < 16384)      { W = W0; hi = w0hi; lo = w0lo; COLS = 128; cin = 128; idx = i; }
    else if (i < 32768) { W = W1; hi = w1hi; lo = w1lo; COLS = 128; cin = 128; idx = i - 16384; }
    else if (i < 40960) { W = W2; hi = w2hi; lo = w2lo; COLS = 64;  cin = 40;  idx = i - 32768; }
    else return;
    int k = idx / COLS, col = idx % COLS;
    float v = (col < cin) ? W[k * cin + col] : 0.f;
    u16 h = f2bf(v);
    u16 l = f2bf(v - bf2f(h));
    int ct = col >> 4, ks = k >> 5, ln = (col & 15) + (((k >> 3) & 3) << 4), j = k & 7;
    int pos = (((ct * 4 + ks) * 64 + ln) << 3) + j;
    hi[pos] = h; lo[pos] = l;
}

// ---------------- CSR build ----------------
__global__ void count_rank_k(const int* __restrict__ dst, int* __restrict__ counts,
                             u16* __restrict__ rank, int e) {
    int i = blockIdx.x * 256 + threadIdx.x;
    if (i < e) rank[i] = (u16)atomicAdd(&counts[dst[i]], 1);
}
__global__ __launch_bounds__(1024) void scan1_k(const int* __restrict__ counts,
                                                int* __restrict__ offs,
                                                int* __restrict__ bsum,
                                                float* __restrict__ dinv, int n) {
    __shared__ int ws[16];
    int tid = threadIdx.x;
    int i = blockIdx.x * 1024 + tid;
    int lane = tid & 63, w = tid >> 6;
    int c = (i < n) ? counts[i] : 0;
    if (i < n) dinv[i] = rsqrtf((float)c + 1.0f);
    int s = c;
#pragma unroll
    for (int o = 1; o < 64; o <<= 1) { int t = __shfl_up(s, o); if (lane >= o) s += t; }
    if (lane == 63) ws[w] = s;
    __syncthreads();
    if (w == 0) {
        int x = (lane < 16) ? ws[lane] : 0;
#pragma unroll
        for (int o = 1; o < 16; o <<= 1) { int t = __shfl_up(x, o); if (lane >= o) x += t; }
        if (lane < 16) ws[lane] = x;
    }
    __syncthreads();
    int base = (w > 0) ? ws[w - 1] : 0;
    int incl = base + s;
    if (i < n) offs[i + 1] = incl;
    if (tid == 1023) bsum[blockIdx.x] = incl;
}
__global__ void scan23_k(int* __restrict__ offs, const int* __restrict__ bsum,
                         int nb, int n) {
    __shared__ int pre[64];
    int tid = threadIdx.x;
    if (tid < 64) {
        int v = (tid < nb) ? bsum[tid] : 0;
#pragma unroll
        for (int o = 1; o < 64; o <<= 1) { int t = __shfl_up(v, o); if (tid >= o) v += t; }
        pre[tid] = v;
    }
    __syncthreads();
    int i = blockIdx.x * 256 + tid;
    if (i == 0) offs[0] = 0;
    if (i < n) {
        int b = i >> 10;
        offs[i + 1] += (b > 0) ? pre[b - 1] : 0;
    }
}

// ---------------- fused: atomic-free CSR fill + layer-1 GEMM ----------------
__global__ __launch_bounds__(256) void fill_gemm1_k(const int* __restrict__ src,
                                                    const int* __restrict__ dst,
                                                    const u16* __restrict__ rank,
                                                    const int* __restrict__ offs,
                                                    u16* __restrict__ csr, int e, int fillBlocks,
                                                    const float* __restrict__ A,
                                                    const u16* __restrict__ Whi,
                                                    const u16* __restrict__ Wlo,
                                                    const float* __restrict__ dinv,
                                                    u16* __restrict__ C, int nrows) {
    if ((int)blockIdx.x < fillBlocks) {
        int i = blockIdx.x * 256 + threadIdx.x;
        if (i < e) csr[offs[dst[i]] + (int)rank[i]] = (u16)src[i];
        return;
    }
    constexpr int COLS = 128;
    int bid = blockIdx.x - fillBlocks;
    int wave = threadIdx.x >> 6, lane = threadIdx.x & 63;
    int r0 = bid * 64 + wave * 16;
    int arow = min(r0 + (lane & 15), nrows - 1);
    int kbase = (lane >> 4) * 8;

    bf16x8 ahi[4], alo[4];
#pragma unroll
    for (int ks = 0; ks < 4; ++ks) {
        const float* ap = &A[(long)arow * 128 + ks * 32 + kbase];
        float4 f0 = *(const float4*)ap;
        float4 f1 = *(const float4*)(ap + 4);
        float fv[8] = {f0.x, f0.y, f0.z, f0.w, f1.x, f1.y, f1.z, f1.w};
#pragma unroll
        for (int j = 0; j < 8; ++j) {
            u16 h = f2bf(fv[j]);
            ahi[ks][j] = (short)h;
            alo[ks][j] = (short)f2bf(fv[j] - bf2f(h));
        }
    }
    float dscale[4];
#pragma unroll
    for (int r = 0; r < 4; ++r) {
        int orow = r0 + (lane >> 4) * 4 + r;
        dscale[r] = (orow < nrows) ? dinv[orow] : 0.f;
    }
#pragma unroll
    for (int ct = 0; ct < COLS / 16; ct += 2) {
        f32x4 acc0 = {0.f, 0.f, 0.f, 0.f}, acc1 = {0.f, 0.f, 0.f, 0.f};
#pragma unroll
        for (int ks = 0; ks < 4; ++ks) {
            int fo0 = ((ct * 4 + ks) * 64 + lane) * 8;
            int fo1 = (((ct + 1) * 4 + ks) * 64 + lane) * 8;
            bf16x8 bhi0 = *(const bf16x8*)&Whi[fo0];
            bf16x8 blo0 = *(const bf16x8*)&Wlo[fo0];
            bf16x8 bhi1 = *(const bf16x8*)&Whi[fo1];
            bf16x8 blo1 = *(const bf16x8*)&Wlo[fo1];
            acc0 = __builtin_amdgcn_mfma_f32_16x16x32_bf16(ahi[ks], bhi0, acc0, 0, 0, 0);
            acc1 = __builtin_amdgcn_mfma_f32_16x16x32_bf16(ahi[ks], bhi1, acc1, 0, 0, 0);
            acc0 = __builtin_amdgcn_mfma_f32_16x16x32_bf16(alo[ks], bhi0, acc0, 0, 0, 0);
            acc1 = __builtin_amdgcn_mfma_f32_16x16x32_bf16(alo[ks], bhi1, acc1, 0, 0, 0);
            acc0 = __builtin_amdgcn_mfma_f32_16x16x32_bf16(ahi[ks], blo0, acc0, 0, 0, 0);
            acc1 = __builtin_amdgcn_mfma_f32_16x16x32_bf16(ahi[ks], blo1, acc1, 0, 0, 0);
        }
#pragma unroll
        for (int r = 0; r < 4; ++r) {
            int orow = r0 + (lane >> 4) * 4 + r;
            if (orow < nrows) {
                C[(long)orow * COLS + ct * 16 + (lane & 15)] = f2bf(acc0[r] * dscale[r]);
                C[(long)orow * COLS + (ct + 1) * 16 + (lane & 15)] = f2bf(acc1[r] * dscale[r]);
            }
        }
    }
}

// ---------------- layers 2/3 GEMM: bf16 A (2 MFMA), row-major bf16 C ----------------
template<int COLS>
__global__ __launch_bounds__(256) void mfma_gemm_bf16a_k(const u16* __restrict__ A,
                                                         const u16* __restrict__ Whi,
                                                         const u16* __restrict__ Wlo,
                                                         const float* __restrict__ dinv,
                                                         u16* __restrict__ C, int nrows) {
    int wave = threadIdx.x >> 6, lane = threadIdx.x & 63;
    int r0 = blockIdx.x * 64 + wave * 16;
    int arow = min(r0 + (lane & 15), nrows - 1);
    int kbase = (lane >> 4) * 8;

    bf16x8 a[4];
#pragma unroll
    for (int ks = 0; ks < 4; ++ks)
        a[ks] = *(const bf16x8*)&A[(long)arow * 128 + ks * 32 + kbase];

    float dscale[4];
#pragma unroll
    for (int r = 0; r < 4; ++r) {
        int orow = r0 + (lane >> 4) * 4 + r;
        dscale[r] = (orow < nrows) ? dinv[orow] : 0.f;
    }
#pragma unroll
    for (int ct = 0; ct < COLS / 16; ct += 2) {
        f32x4 acc0 = {0.f, 0.f, 0.f, 0.f}, acc1 = {0.f, 0.f, 0.f, 0.f};
#pragma unroll
        for (int ks = 0; ks < 4; ++ks) {
            int fo0 = ((ct * 4 + ks) * 64 + lane) * 8;
            int fo1 = (((ct + 1) * 4 + ks) * 64 + lane) * 8;
            bf16x8 bhi0 = *(const bf16x8*)&Whi[fo0];
            bf16x8 blo0 = *(const bf16x8*)&Wlo[fo0];
            bf16x8 bhi1 = *(const bf16x8*)&Whi[fo1];
            bf16x8 blo1 = *(const bf16x8*)&Wlo[fo1];
            acc0 = __builtin_amdgcn_mfma_f32_16x16x32_bf16(a[ks], bhi0, acc0, 0, 0, 0);
            acc1 = __builtin_amdgcn_mfma_f32_16x16x32_bf16(a[ks], bhi1, acc1, 0, 0, 0);
            acc0 = __builtin_amdgcn_mfma_f32_16x16x32_bf16(a[ks], blo0, acc0, 0, 0, 0);
            acc1 = __builtin_amdgcn_mfma_f32_16x16x32_bf16(a[ks], blo1, acc1, 0, 0, 0);
        }
#pragma unroll
        for (int r = 0; r < 4; ++r) {
            int orow = r0 + (lane >> 4) * 4 + r;
            if (orow < nrows) {
                C[(long)orow * COLS + ct * 16 + (lane & 15)] = f2bf(acc0[r] * dscale[r]);
                C[(long)orow * COLS + (ct + 1) * 16 + (lane & 15)] = f2bf(acc1[r] * dscale[r]);
            }
        }
    }
}

// ---------------- agg + bias + LN + ReLU: paired-edge dwordx2 gather ----------------
// 32 lanes x 8B per edge row (128 bf16); lane half=l>>5 handles edge k+half; w=l&31 -> feats 4w..4w+3
__global__ __launch_bounds__(256) void agg_ln_relu_k(const u16* __restrict__ Cs,
                                                     const int* __restrict__ offs,
                                                     const u16* __restrict__ csr,
                                                     const float* __restrict__ dinv,
                                                     const float* __restrict__ bias,
                                                     const float* __restrict__ g,
                                                     const float* __restrict__ b,
                                                     u16* __restrict__ out, int n) {
    int wid = (blockIdx.x * 256 + threadIdx.x) >> 6;
    int lane = threadIdx.x & 63;
    if (wid >= n) return;
    const u32* C2 = (const u32*)Cs;  // 64 u32 per row
    int half = lane >> 5;
    int w = lane & 31;
    float a0 = 0.f, a1 = 0.f, a2 = 0.f, a3 = 0.f;
    float c0 = 0.f, c1 = 0.f, c2 = 0.f, c3 = 0.f;
    if (half == 0) {  // self term
        uint2 u = *(const uint2*)&C2[(size_t)wid * 64 + 2 * w];
        a0 = pk_lo(u.x); a1 = pk_hi(u.x); a2 = pk_lo(u.y); a3 = pk_hi(u.y);
    }
    int beg = offs[wid], end = offs[wid + 1];
    for (int j = beg; j < end; j += 64) {
        int take = min(64, end - j);
        int myidx = (lane < take) ? (int)csr[j + lane] : 0;
        int k = 0;
        for (; k + 16 <= take; k += 16) {
#pragma unroll
            for (int it = 0; it < 8; ++it) {
                int s = __shfl(myidx, k + it * 2 + half);
                uint2 u = *(const uint2*)&C2[(size_t)s * 64 + 2 * w];
                if (it & 1) { c0 += pk_lo(u.x); c1 += pk_hi(u.x); c2 += pk_lo(u.y); c3 += pk_hi(u.y); }
                else        { a0 += pk_lo(u.x); a1 += pk_hi(u.x); a2 += pk_lo(u.y); a3 += pk_hi(u.y); }
            }
        }
        for (; k < take; k += 2) {
            int e = k + half;
            bool v = e < take;
            int s = __shfl(myidx, v ? e : 0);
            if (v) {
                uint2 u = *(const uint2*)&C2[(size_t)s * 64 + 2 * w];
                a0 += pk_lo(u.x); a1 += pk_hi(u.x); a2 += pk_lo(u.y); a3 += pk_hi(u.y);
            }
        }
    }
    a0 += c0; a1 += c1; a2 += c2; a3 += c3;
    a0 += __shfl_xor(a0, 32); a1 += __shfl_xor(a1, 32);
    a2 += __shfl_xor(a2, 32); a3 += __shfl_xor(a3, 32);
    float dv = dinv[wid];
    float4 bi = ((const float4*)bias)[w];
    float t0 = a0 * dv + bi.x, t1 = a1 * dv + bi.y;
    float t2 = a2 * dv + bi.z, t3 = a3 * dv + bi.w;
    float s4 = t0 + t1 + t2 + t3;
#pragma unroll
    for (int o = 1; o < 32; o <<= 1) s4 += __shfl_xor(s4, o);
    float mu = s4 * (1.f / 128.f);
    float d0 = t0 - mu, d1 = t1 - mu, d2 = t2 - mu, d3 = t3 - mu;
    float q = d0 * d0 + d1 * d1 + d2 * d2 + d3 * d3;
#pragma unroll
    for (int o = 1; o < 32; o <<= 1) q += __shfl_xor(q, o);
    float rstd = rsqrtf(q * (1.f / 128.f) + 1e-5f);
    float4 gv = ((const float4*)g)[w];
    float4 bv = ((const float4*)b)[w];
    float y0 = fmaxf(0.f, d0 * rstd * gv.x + bv.x);
    float y1 = fmaxf(0.f, d1 * rstd * gv.y + bv.y);
    float y2 = fmaxf(0.f, d2 * rstd * gv.z + bv.z);
    float y3 = fmaxf(0.f, d3 * rstd * gv.w + bv.w);
    if (half == 0) {
        uint2 o2;
        o2.x = ((u32)f2bf(y1) << 16) | f2bf(y0);
        o2.y = ((u32)f2bf(y3) << 16) | f2bf(y2);
        *(uint2*)&((u32*)out)[(size_t)wid * 64 + 2 * w] = o2;
    }
}

// ---------------- agg + bias + log_softmax: 4-edge dwordx2 gather (64-col rows) ----------------
// 16 lanes x 8B per edge row (64 bf16); slot=l>>4 handles edge k+slot; w=l&15 -> feats 4w..4w+3
__global__ __launch_bounds__(256) void agg_lsm_k(const u16* __restrict__ Cs,
                                                 const int* __restrict__ offs,
                                                 const u16* __restrict__ csr,
                                                 const float* __restrict__ dinv,
                                                 const float* __restrict__ b2,
                                                 float* __restrict__ out, int n) {
    int wid = (blockIdx.x * 256 + threadIdx.x) >> 6;
    int lane = threadIdx.x & 63;
    if (wid >= n) return;
    const u32* C2 = (const u32*)Cs;  // 32 u32 per row
    int slot = lane >> 4;
    int w = lane & 15;
    float a0 = 0.f, a1 = 0.f, a2 = 0.f, a3 = 0.f;
    float c0 = 0.f, c1 = 0.f, c2 = 0.f, c3 = 0.f;
    if (slot == 0) {  // self term
        uint2 u = *(const uint2*)&C2[(size_t)wid * 32 + 2 * w];
        a0 = pk_lo(u.x); a1 = pk_hi(u.x); a2 = pk_lo(u.y); a3 = pk_hi(u.y);
    }
    int beg = offs[wid], end = offs[wid + 1];
    for (int j = beg; j < end; j += 64) {
        int take = min(64, end - j);
        int myidx = (lane < take) ? (int)csr[j + lane] : 0;
        int k = 0;
        for (; k + 16 <= take; k += 16) {
#pragma unroll
            for (int it = 0; it < 4; ++it) {
                int s = __shfl(myidx, k + it * 4 + slot);
                uint2 u = *(const uint2*)&C2[(size_t)s * 32 + 2 * w];
                if (it & 1) { c0 += pk_lo(u.x); c1 += pk_hi(u.x); c2 += pk_lo(u.y); c3 += pk_hi(u.y); }
                else        { a0 += pk_lo(u.x); a1 += pk_hi(u.x); a2 += pk_lo(u.y); a3 += pk_hi(u.y); }
            }
        }
        for (; k < take; k += 4) {
            int e = k + slot;
            bool v = e < take;
            int s = __shfl(myidx, v ? e : 0);
            if (v) {
                uint2 u = *(const uint2*)&C2[(size_t)s * 32 + 2 * w];
                a0 += pk_lo(u.x); a1 += pk_hi(u.x); a2 += pk_lo(u.y); a3 += pk_hi(u.y);
            }
        }
    }
    a0 += c0; a1 += c1; a2 += c2; a3 += c3;
#pragma unroll
    for (int m2 = 16; m2 < 64; m2 <<= 1) {
        a0 += __shfl_xor(a0, m2); a1 += __shfl_xor(a1, m2);
        a2 += __shfl_xor(a2, m2); a3 += __shfl_xor(a3, m2);
    }
    // feats f = 4w..4w+3; valid iff w < 10 (OUT=40)
    float dv = dinv[wid];
    float v0 = -INFINITY, v1 = -INFINITY, v2 = -INFINITY, v3 = -INFINITY;
    if (w < 10) {
        float4 bb = ((const float4*)b2)[w];
        v0 = a0 * dv + bb.x; v1 = a1 * dv + bb.y;
        v2 = a2 * dv + bb.z; v3 = a3 * dv + bb.w;
    }
    float m = fmaxf(fmaxf(v0, v1), fmaxf(v2, v3));
#pragma unroll
    for (int o = 1; o < 16; o <<= 1) m = fmaxf(m, __shfl_xor(m, o));
    float es = 0.f;
    if (w < 10) es = expf(v0 - m) + expf(v1 - m) + expf(v2 - m) + expf(v3 - m);
#pragma unroll
    for (int o = 1; o < 16; o <<= 1) es += __shfl_xor(es, o);
    float ls = logf(es);
    if (slot == 0 && w < 10) {
        float4 r = make_float4(v0 - m - ls, v1 - m - ls, v2 - m - ls, v3 - m - ls);
        *(float4*)&out[(size_t)wid * 40 + 4 * w] = r;
    }
}

extern "C" void kernel_launch(void* const* d_in, const int* in_sizes, int n_in,
                              void* d_out, int out_size, void* d_ws, size_t ws_size,
                              hipStream_t stream) {
    const float* x    = (const float*)d_in[0];
    const float* W0   = (const float*)d_in[1];
    const float* b0   = (const float*)d_in[2];
    const float* W1   = (const float*)d_in[3];
    const float* b1   = (const float*)d_in[4];
    const float* W2   = (const float*)d_in[5];
    const float* b2   = (const float*)d_in[6];
    const float* ln1g = (const float*)d_in[7];
    const float* ln1b = (const float*)d_in[8];
    const float* ln2g = (const float*)d_in[9];
    const float* ln2b = (const float*)d_in[10];
    const int*   ei   = (const int*)d_in[11];

    const int N = in_sizes[0] / 128;   // 50000
    const int E = in_sizes[11] / 2;    // 800000
    const int* esrc = ei;
    const int* edst = ei + E;
    float* out = (float*)d_out;

    const int Npad = ((N + 255) / 256) * 256;

    int* counts  = (int*)d_ws;                        // Npad
    int* offs    = counts + Npad;                     // Npad (N+1 used)
    int* bsum    = offs + Npad;                       // 64
    u16* rank16  = (u16*)(bsum + 64);                 // E
    u16* csr16   = rank16 + E;                        // E
    float* dinv  = (float*)(csr16 + E);               // Npad
    u16* bufA    = (u16*)(dinv + Npad);               // N*128 bf16 (Cs)
    u16* bufB    = bufA + (size_t)N * 128;            // N*128 bf16 (h)
    u16* w0hi    = bufB + (size_t)N * 128;
    u16* w0lo    = w0hi + 16384;
    u16* w1hi    = w0lo + 16384;
    u16* w1lo    = w1hi + 16384;
    u16* w2hi    = w1lo + 16384;
    u16* w2lo    = w2hi + 8192;

    dim3 blk(256);
    int gN = (N + 255) / 256, gE = (E + 255) / 256;
    int nb1024 = (N + 1023) / 1024;
    int gG = (N + 63) / 64;
    int gW = (N + 3) / 4;

    // 1. zero + weight prepack
    init_k<<<gN + 160, blk, 0, stream>>>(counts, N, gN, W0, W1, W2,
                                         w0hi, w0lo, w1hi, w1lo, w2hi, w2lo);
    // 2. count + rank
    count_rank_k<<<gE, blk, 0, stream>>>(edst, counts, rank16, E);
    // 3. block-local scan + dinv
    scan1_k<<<nb1024, 1024, 0, stream>>>(counts, offs, bsum, dinv, N);
    // 4. cross-block scan fixup
    scan23_k<<<gN, blk, 0, stream>>>(offs, bsum, nb1024, N);
    // 5. CSR fill + layer-1 GEMM (fused dispatch)
    fill_gemm1_k<<<gE + gG, blk, 0, stream>>>(esrc, edst, rank16, offs, csr16, E, gE,
                                              x, w0hi, w0lo, dinv, bufA, N);
    // 6. agg + LN1 + ReLU
    agg_ln_relu_k<<<gW, blk, 0, stream>>>(bufA, offs, csr16, dinv, b0, ln1g, ln1b, bufB, N);
    // 7. layer-2 GEMM
    mfma_gemm_bf16a_k<128><<<gG, blk, 0, stream>>>(bufB, w1hi, w1lo, dinv, bufA, N);
    // 8. agg + LN2 + ReLU
    agg_ln_relu_k<<<gW, blk, 0, stream>>>(bufA, offs, csr16, dinv, b1, ln2g, ln2b, bufB, N);
    // 9. layer-3 GEMM
    mfma_gemm_bf16a_k<64><<<gG, blk, 0, stream>>>(bufB, w2hi, w2lo, dinv, bufA, N);
    // 10. agg + bias + log_softmax
    agg_lsm_k<<<gW, blk, 0, stream>>>(bufA, offs, csr16, dinv, b2, out, N);
}